// Round 1
// baseline (590.134 us; speedup 1.0000x reference)
//
#include <hip/hip_runtime.h>
#include <hip/hip_bf16.h>

#define D 128  // D_IN == D_OUT == 128

// ---------------- Kernel 1: h = nf @ W + b ; writes h to ws and d_out ----
// Block: 256 threads, tile = 32 nodes x 128 cols. W fully staged in LDS.
__global__ __launch_bounds__(256) void gemm_h_kernel(
    const float* __restrict__ nf, const float* __restrict__ W,
    const float* __restrict__ b, float* __restrict__ h,
    float* __restrict__ out, int n_nodes) {
  __shared__ float Ws[D * D];     // 64 KB
  __shared__ float Xs[32 * D];    // 16 KB
  const int tid = threadIdx.x;

  // Load W (128x128 f32) into LDS as float4
  const float4* W4 = (const float4*)W;
  float4* Ws4 = (float4*)Ws;
  #pragma unroll
  for (int i = 0; i < 16; ++i) Ws4[tid + i * 256] = W4[tid + i * 256];

  // Load 32-node X tile
  const int nodeBase = blockIdx.x * 32;
  const float4* nf4 = (const float4*)(nf + (size_t)nodeBase * D);
  float4* Xs4 = (float4*)Xs;
  #pragma unroll
  for (int i = 0; i < 4; ++i) Xs4[tid + i * 256] = nf4[tid + i * 256];
  __syncthreads();

  const int tx = tid & 31;   // column group: cols tx*4 .. tx*4+3
  const int ty = tid >> 5;   // node group: nodes ty*4 .. ty*4+3

  float acc[4][4];
  #pragma unroll
  for (int i = 0; i < 4; ++i)
    #pragma unroll
    for (int j = 0; j < 4; ++j) acc[i][j] = 0.f;

  #pragma unroll 4
  for (int k = 0; k < D; ++k) {
    const float4 wv = *(const float4*)&Ws[k * D + tx * 4];  // ds_read_b128
    #pragma unroll
    for (int i = 0; i < 4; ++i) {
      const float xv = Xs[(ty * 4 + i) * D + k];  // broadcast-ish
      acc[i][0] = fmaf(xv, wv.x, acc[i][0]);
      acc[i][1] = fmaf(xv, wv.y, acc[i][1]);
      acc[i][2] = fmaf(xv, wv.z, acc[i][2]);
      acc[i][3] = fmaf(xv, wv.w, acc[i][3]);
    }
  }

  const float4 bv = *(const float4*)&b[tx * 4];
  #pragma unroll
  for (int i = 0; i < 4; ++i) {
    const size_t n = (size_t)(nodeBase + ty * 4 + i);
    float4 r;
    r.x = acc[i][0] + bv.x;
    r.y = acc[i][1] + bv.y;
    r.z = acc[i][2] + bv.z;
    r.w = acc[i][3] + bv.w;
    *(float4*)&h[n * D + tx * 4] = r;
    *(float4*)&out[n * D + tx * 4] = r;  // accumulator init (self term)
  }
}

// ---------------- Kernel 2: per-edge message + scatter-add ----------------
// One wave (64 lanes) per edge; lane handles 2 dims (float2).
__global__ __launch_bounds__(256) void edge_scatter_kernel(
    const int* __restrict__ eidx, const int* __restrict__ etype,
    const float* __restrict__ eemb, const float* __restrict__ h,
    float* __restrict__ out, int n_edges) {
  const int gid = blockIdx.x * 256 + threadIdx.x;
  const int e = gid >> 6;
  const int lane = gid & 63;
  if (e >= n_edges) return;

  const int src = eidx[e];
  const int tgt = eidx[n_edges + e];
  const int et = etype[e];

  const float2 hv = ((const float2*)(h + (size_t)src * D))[lane];
  const float2 ev = ((const float2*)(eemb + (size_t)et * D))[lane];

  float* op = out + (size_t)tgt * D + lane * 2;
  unsafeAtomicAdd(op, hv.x + ev.x);
  unsafeAtomicAdd(op + 1, hv.y + ev.y);
}

// ---------------- Kernel 3: in-place ReLU ---------------------------------
__global__ __launch_bounds__(256) void relu_kernel(float* __restrict__ out,
                                                   int n4) {
  int i = blockIdx.x * 256 + threadIdx.x;
  const int stride = gridDim.x * 256;
  float4* p = (float4*)out;
  for (; i < n4; i += stride) {
    float4 v = p[i];
    v.x = fmaxf(v.x, 0.f);
    v.y = fmaxf(v.y, 0.f);
    v.z = fmaxf(v.z, 0.f);
    v.w = fmaxf(v.w, 0.f);
    p[i] = v;
  }
}

extern "C" void kernel_launch(void* const* d_in, const int* in_sizes, int n_in,
                              void* d_out, int out_size, void* d_ws,
                              size_t ws_size, hipStream_t stream) {
  const float* nf   = (const float*)d_in[0];  // (N, 128) f32
  const int*   eidx = (const int*)d_in[1];    // (2, E) int
  const int*   etyp = (const int*)d_in[2];    // (E,) int
  const float* eemb = (const float*)d_in[3];  // (64, 128) f32
  const float* W    = (const float*)d_in[4];  // (128, 128) f32
  const float* b    = (const float*)d_in[5];  // (128,) f32

  const int n_nodes = in_sizes[0] / D;
  const int n_edges = in_sizes[2];

  float* out = (float*)d_out;
  float* h   = (float*)d_ws;  // n_nodes*128 f32 = 51.2 MB scratch

  // 1) h = nf @ W + b  (h -> ws, and init out = h)
  const int gemm_blocks = (n_nodes + 31) / 32;  // 3125 (exact)
  gemm_h_kernel<<<gemm_blocks, 256, 0, stream>>>(nf, W, b, h, out, n_nodes);

  // 2) scatter messages: out[tgt] += h[src] + eemb[etype]
  const long long total_threads = (long long)n_edges * 64;
  const int edge_blocks = (int)((total_threads + 255) / 256);  // 156250
  edge_scatter_kernel<<<edge_blocks, 256, 0, stream>>>(eidx, etyp, eemb, h,
                                                       out, n_edges);

  // 3) ReLU in place
  const int n4 = n_nodes * D / 4;
  relu_kernel<<<2048, 256, 0, stream>>>(out, n4);
}

// Round 2
// 210.932 us; speedup vs baseline: 2.7977x; 2.7977x over previous
//
#include <hip/hip_runtime.h>
#include <hip/hip_bf16.h>

#define D 128  // D_IN == D_OUT == 128

// ============================ GEMM: h = nf @ W + b ========================
// Block: 256 threads, tile = 32 nodes x 128 cols. W fully staged in LDS.
__global__ __launch_bounds__(256) void gemm_h_kernel(
    const float* __restrict__ nf, const float* __restrict__ W,
    const float* __restrict__ b, float* __restrict__ h, int n_nodes) {
  __shared__ float Ws[D * D];     // 64 KB
  __shared__ float Xs[32 * D];    // 16 KB
  const int tid = threadIdx.x;

  const float4* W4 = (const float4*)W;
  float4* Ws4 = (float4*)Ws;
  #pragma unroll
  for (int i = 0; i < 16; ++i) Ws4[tid + i * 256] = W4[tid + i * 256];

  const int nodeBase = blockIdx.x * 32;
  const float4* nf4 = (const float4*)(nf + (size_t)nodeBase * D);
  float4* Xs4 = (float4*)Xs;
  #pragma unroll
  for (int i = 0; i < 4; ++i) Xs4[tid + i * 256] = nf4[tid + i * 256];
  __syncthreads();

  const int tx = tid & 31;   // cols tx*4 .. tx*4+3
  const int ty = tid >> 5;   // nodes ty*4 .. ty*4+3

  float acc[4][4];
  #pragma unroll
  for (int i = 0; i < 4; ++i)
    #pragma unroll
    for (int j = 0; j < 4; ++j) acc[i][j] = 0.f;

  #pragma unroll 4
  for (int k = 0; k < D; ++k) {
    const float4 wv = *(const float4*)&Ws[k * D + tx * 4];
    #pragma unroll
    for (int i = 0; i < 4; ++i) {
      const float xv = Xs[(ty * 4 + i) * D + k];
      acc[i][0] = fmaf(xv, wv.x, acc[i][0]);
      acc[i][1] = fmaf(xv, wv.y, acc[i][1]);
      acc[i][2] = fmaf(xv, wv.z, acc[i][2]);
      acc[i][3] = fmaf(xv, wv.w, acc[i][3]);
    }
  }

  const float4 bv = *(const float4*)&b[tx * 4];
  #pragma unroll
  for (int i = 0; i < 4; ++i) {
    const size_t n = (size_t)(nodeBase + ty * 4 + i);
    float4 r;
    r.x = acc[i][0] + bv.x;
    r.y = acc[i][1] + bv.y;
    r.z = acc[i][2] + bv.z;
    r.w = acc[i][3] + bv.w;
    *(float4*)&h[n * D + tx * 4] = r;
  }
}

// ============================ CSR build ====================================
__global__ __launch_bounds__(256) void zero_counts_kernel(int* __restrict__ c,
                                                          int n) {
  int i = blockIdx.x * 256 + threadIdx.x;
  if (i < n) c[i] = 0;
}

__global__ __launch_bounds__(256) void hist_kernel(
    const int* __restrict__ eidx, int* __restrict__ counts, int n_edges) {
  int e = blockIdx.x * 256 + threadIdx.x;
  if (e < n_edges) atomicAdd(&counts[eidx[n_edges + e]], 1);
}

// scan pass 1: per-block (1024 elems) exclusive scan; blockSums[b] = total
__global__ __launch_bounds__(256) void scan1_kernel(
    const int* __restrict__ counts, int* __restrict__ offsets,
    int* __restrict__ blockSums, int n) {
  __shared__ int lds[256];
  const int tid = threadIdx.x;
  const int base = blockIdx.x * 1024 + tid * 4;
  int v[4];
  #pragma unroll
  for (int k = 0; k < 4; ++k) v[k] = (base + k < n) ? counts[base + k] : 0;
  int s = v[0] + v[1] + v[2] + v[3];
  lds[tid] = s;
  for (int off = 1; off < 256; off <<= 1) {
    __syncthreads();
    int t = (tid >= off) ? lds[tid - off] : 0;
    __syncthreads();
    lds[tid] += t;
  }
  __syncthreads();
  int excl = lds[tid] - s;  // exclusive prefix of this thread's group
  int run = excl;
  #pragma unroll
  for (int k = 0; k < 4; ++k) {
    if (base + k < n) offsets[base + k] = run;
    run += v[k];
  }
  if (tid == 255) blockSums[blockIdx.x] = lds[255];
}

// scan pass 2: single block exclusive scan of block sums (nb <= 1024)
__global__ __launch_bounds__(1024) void scan2_kernel(int* __restrict__ blockSums,
                                                     int* __restrict__ blockOffs,
                                                     int nb) {
  __shared__ int lds[1024];
  const int tid = threadIdx.x;
  int v = (tid < nb) ? blockSums[tid] : 0;
  lds[tid] = v;
  for (int off = 1; off < 1024; off <<= 1) {
    __syncthreads();
    int t = (tid >= off) ? lds[tid - off] : 0;
    __syncthreads();
    lds[tid] += t;
  }
  __syncthreads();
  if (tid < nb) blockOffs[tid] = lds[tid] - v;
}

// scan pass 3: add block offsets; copy to cursor; finalize offsets[n]
__global__ __launch_bounds__(256) void scan3_kernel(
    int* __restrict__ offsets, int* __restrict__ cursor,
    const int* __restrict__ blockOffs, int n, int n_edges) {
  const int tid = threadIdx.x;
  const int add = blockOffs[blockIdx.x];
  const int base = blockIdx.x * 1024 + tid * 4;
  #pragma unroll
  for (int k = 0; k < 4; ++k) {
    int i = base + k;
    if (i < n) {
      int o = offsets[i] + add;
      offsets[i] = o;
      cursor[i] = o;
    }
  }
  if (blockIdx.x == 0 && tid == 0) offsets[n] = n_edges;
}

// scatter: packed[pos] = src | (etype << 17)   (src < 2^17, etype < 64)
__global__ __launch_bounds__(256) void scatter_kernel(
    const int* __restrict__ eidx, const int* __restrict__ etype,
    int* __restrict__ cursor, unsigned int* __restrict__ packed, int n_edges) {
  int e = blockIdx.x * 256 + threadIdx.x;
  if (e >= n_edges) return;
  const int src = eidx[e];
  const int tgt = eidx[n_edges + e];
  const int et = etype[e];
  const int pos = atomicAdd(&cursor[tgt], 1);
  packed[pos] = (unsigned int)src | ((unsigned int)et << 17);
}

// ===================== aggregate: one wave per node ========================
// out[n] = relu(h[n] + sum_{edges->n} (h[src] + emb[etype]))
__global__ __launch_bounds__(256) void aggregate_kernel(
    const int* __restrict__ offsets, const unsigned int* __restrict__ packed,
    const float* __restrict__ eemb, const float* __restrict__ h,
    float* __restrict__ out, int n_nodes) {
  const int gid = blockIdx.x * 256 + threadIdx.x;
  const int n = gid >> 6;
  const int lane = gid & 63;
  if (n >= n_nodes) return;

  const float2* h2 = (const float2*)h;
  const float2* e2 = (const float2*)eemb;

  const int start = offsets[n];
  const int end = offsets[n + 1];

  float2 acc = h2[(size_t)n * 64 + lane];  // self contribution
  for (int j = start; j < end; ++j) {
    const unsigned int p = packed[j];
    const int src = (int)(p & 0x1FFFFu);
    const int et = (int)(p >> 17);
    const float2 hv = h2[(size_t)src * 64 + lane];
    const float2 ev = e2[(size_t)et * 64 + lane];
    acc.x += hv.x + ev.x;
    acc.y += hv.y + ev.y;
  }
  float2 r;
  r.x = fmaxf(acc.x, 0.f);
  r.y = fmaxf(acc.y, 0.f);
  ((float2*)out)[(size_t)n * 64 + lane] = r;
}

// ===========================================================================
extern "C" void kernel_launch(void* const* d_in, const int* in_sizes, int n_in,
                              void* d_out, int out_size, void* d_ws,
                              size_t ws_size, hipStream_t stream) {
  const float* nf   = (const float*)d_in[0];  // (N, 128) f32
  const int*   eidx = (const int*)d_in[1];    // (2, E) int
  const int*   etyp = (const int*)d_in[2];    // (E,) int
  const float* eemb = (const float*)d_in[3];  // (64, 128) f32
  const float* W    = (const float*)d_in[4];  // (128, 128) f32
  const float* b    = (const float*)d_in[5];  // (128,) f32

  const int n_nodes = in_sizes[0] / D;  // 100000
  const int n_edges = in_sizes[2];      // 625000

  float* out = (float*)d_out;

  // workspace layout (~54.9 MB total)
  char* base = (char*)d_ws;
  float* h = (float*)base;                               // N*128 f32 = 51.2 MB
  int* counts = (int*)(base + (size_t)n_nodes * D * 4);  // N ints
  int* offsets = counts + n_nodes;                       // N+1 ints
  int* cursor = offsets + (n_nodes + 1);                 // N ints
  int* blockSums = cursor + n_nodes;                     // <=1024 ints
  int* blockOffs = blockSums + 1024;                     // <=1024 ints
  unsigned int* packed = (unsigned int*)(blockOffs + 1024);  // E uints

  const int nb = (n_nodes + 1023) / 1024;  // 98 scan blocks

  // 1) GEMM h = nf @ W + b
  gemm_h_kernel<<<(n_nodes + 31) / 32, 256, 0, stream>>>(nf, W, b, h, n_nodes);

  // 2) CSR build: histogram -> scan -> scatter packed (src|etype)
  zero_counts_kernel<<<(n_nodes + 255) / 256, 256, 0, stream>>>(counts, n_nodes);
  hist_kernel<<<(n_edges + 255) / 256, 256, 0, stream>>>(eidx, counts, n_edges);
  scan1_kernel<<<nb, 256, 0, stream>>>(counts, offsets, blockSums, n_nodes);
  scan2_kernel<<<1, 1024, 0, stream>>>(blockSums, blockOffs, nb);
  scan3_kernel<<<nb, 256, 0, stream>>>(offsets, cursor, blockOffs, n_nodes,
                                       n_edges);
  scatter_kernel<<<(n_edges + 255) / 256, 256, 0, stream>>>(eidx, etyp, cursor,
                                                            packed, n_edges);

  // 3) aggregate + self + ReLU (one wave per node, no atomics)
  const long long aggThreads = (long long)n_nodes * 64;
  aggregate_kernel<<<(int)((aggThreads + 255) / 256), 256, 0, stream>>>(
      offsets, packed, eemb, h, out, n_nodes);
}

// Round 3
// 161.101 us; speedup vs baseline: 3.6631x; 1.3093x over previous
//
#include <hip/hip_runtime.h>
#include <hip/hip_bf16.h>

#define D 128  // D_IN == D_OUT == 128

typedef __attribute__((ext_vector_type(8))) short short8v;   // 8 bf16 (4 VGPR)
typedef __attribute__((ext_vector_type(4))) float float4v;   // MFMA acc

__device__ __forceinline__ unsigned short f2bf(float f) {
  union { float f; unsigned int u; } v; v.f = f;
  unsigned int r = v.u + 0x7fffu + ((v.u >> 16) & 1u);  // RNE
  return (unsigned short)(r >> 16);
}
__device__ __forceinline__ float bf2f(unsigned int bits16) {
  union { unsigned int u; float f; } v; v.u = bits16 << 16;
  return v.f;
}

// ================= Wt prep: Wt[n][k] = bf16(W[k][n]) ======================
__global__ __launch_bounds__(256) void wt_prep_kernel(
    const float* __restrict__ W, unsigned short* __restrict__ Wt) {
  int i = blockIdx.x * 256 + threadIdx.x;  // i = n*128 + k
  if (i < D * D) Wt[i] = f2bf(W[(i & 127) * D + (i >> 7)]);
}

// ================= GEMM: h_bf = bf16(nf @ W + b) via MFMA =================
// Block 256 = 4 waves; tile = 32 nodes x 128 cols.
// wave w: rows (w&1)*16..+16, cols (w>>1)*64..+64 (4 col-tiles of 16).
#define XS_STRIDE 136  // 128 + 8 bf16 pad
__global__ __launch_bounds__(256) void gemm_h_kernel(
    const float* __restrict__ nf, const unsigned short* __restrict__ Wt,
    const float* __restrict__ b, unsigned short* __restrict__ h_bf,
    int n_nodes) {
  __shared__ unsigned short Xs[32 * XS_STRIDE];  // 8.7 KB
  const int tid = threadIdx.x;
  const int nodeBase = blockIdx.x * 32;

  // ---- stage X tile (32x128 f32 -> bf16 LDS), coalesced ----
  #pragma unroll
  for (int s = 0; s < 2; ++s) {
    const int row = (tid >> 4) + s * 16;
    const int col = (tid & 15) * 8;
    const float4* p =
        (const float4*)&nf[(size_t)(nodeBase + row) * D + col];
    float4 a = p[0], c = p[1];
    short8v sv;
    sv[0] = (short)f2bf(a.x); sv[1] = (short)f2bf(a.y);
    sv[2] = (short)f2bf(a.z); sv[3] = (short)f2bf(a.w);
    sv[4] = (short)f2bf(c.x); sv[5] = (short)f2bf(c.y);
    sv[6] = (short)f2bf(c.z); sv[7] = (short)f2bf(c.w);
    *(short8v*)&Xs[row * XS_STRIDE + col] = sv;
  }

  const int w = tid >> 6;
  const int l = tid & 63;
  const int m = l & 15;    // fragment row/col index
  const int q = l >> 4;    // k-quarter
  const int r0 = (w & 1) * 16;
  const int c0 = (w >> 1) * 64;

  // ---- B fragments from global Wt (L2-hot 32KB), hoisted ----
  short8v bfrag[4][4];  // [col-tile][k-chunk]
  float bias[4];
  #pragma unroll
  for (int ct = 0; ct < 4; ++ct) {
    const int n = c0 + ct * 16 + m;
    bias[ct] = b[n];
    #pragma unroll
    for (int kc = 0; kc < 4; ++kc)
      bfrag[ct][kc] = *(const short8v*)&Wt[n * D + kc * 32 + q * 8];
  }

  float4v acc[4] = {{0,0,0,0},{0,0,0,0},{0,0,0,0},{0,0,0,0}};
  __syncthreads();

  #pragma unroll
  for (int kc = 0; kc < 4; ++kc) {
    const short8v av =
        *(const short8v*)&Xs[(r0 + m) * XS_STRIDE + kc * 32 + q * 8];
    #pragma unroll
    for (int ct = 0; ct < 4; ++ct)
      acc[ct] = __builtin_amdgcn_mfma_f32_16x16x32_bf16(av, bfrag[ct][kc],
                                                        acc[ct], 0, 0, 0);
  }

  // ---- epilogue: + bias, -> bf16, store ----
  #pragma unroll
  for (int ct = 0; ct < 4; ++ct) {
    const int col = c0 + ct * 16 + m;
    #pragma unroll
    for (int r = 0; r < 4; ++r) {
      const int node = nodeBase + r0 + q * 4 + r;
      h_bf[(size_t)node * D + col] = f2bf(acc[ct][r] + bias[ct]);
    }
  }
}

// ============================ CSR build ====================================
__global__ __launch_bounds__(256) void hist_kernel(
    const int* __restrict__ eidx, int* __restrict__ counts, int n_edges) {
  int e = blockIdx.x * 256 + threadIdx.x;
  if (e < n_edges) atomicAdd(&counts[eidx[n_edges + e]], 1);
}

__global__ __launch_bounds__(256) void scan1_kernel(
    const int* __restrict__ counts, int* __restrict__ offsets,
    int* __restrict__ blockSums, int n) {
  __shared__ int lds[256];
  const int tid = threadIdx.x;
  const int base = blockIdx.x * 1024 + tid * 4;
  int v[4];
  #pragma unroll
  for (int k = 0; k < 4; ++k) v[k] = (base + k < n) ? counts[base + k] : 0;
  int s = v[0] + v[1] + v[2] + v[3];
  lds[tid] = s;
  for (int off = 1; off < 256; off <<= 1) {
    __syncthreads();
    int t = (tid >= off) ? lds[tid - off] : 0;
    __syncthreads();
    lds[tid] += t;
  }
  __syncthreads();
  int run = lds[tid] - s;
  #pragma unroll
  for (int k = 0; k < 4; ++k) {
    if (base + k < n) offsets[base + k] = run;
    run += v[k];
  }
  if (tid == 255) blockSums[blockIdx.x] = lds[255];
}

__global__ __launch_bounds__(1024) void scan2_kernel(int* __restrict__ blockSums,
                                                     int* __restrict__ blockOffs,
                                                     int nb) {
  __shared__ int lds[1024];
  const int tid = threadIdx.x;
  int v = (tid < nb) ? blockSums[tid] : 0;
  lds[tid] = v;
  for (int off = 1; off < 1024; off <<= 1) {
    __syncthreads();
    int t = (tid >= off) ? lds[tid - off] : 0;
    __syncthreads();
    lds[tid] += t;
  }
  __syncthreads();
  if (tid < nb) blockOffs[tid] = lds[tid] - v;
}

__global__ __launch_bounds__(256) void scan3_kernel(
    int* __restrict__ offsets, int* __restrict__ cursor,
    const int* __restrict__ blockOffs, int n, int n_edges) {
  const int tid = threadIdx.x;
  const int add = blockOffs[blockIdx.x];
  const int base = blockIdx.x * 1024 + tid * 4;
  #pragma unroll
  for (int k = 0; k < 4; ++k) {
    int i = base + k;
    if (i < n) {
      int o = offsets[i] + add;
      offsets[i] = o;
      cursor[i] = o;
    }
  }
  if (blockIdx.x == 0 && tid == 0) offsets[n] = n_edges;
}

__global__ __launch_bounds__(256) void scatter_kernel(
    const int* __restrict__ eidx, const int* __restrict__ etype,
    int* __restrict__ cursor, unsigned int* __restrict__ packed, int n_edges) {
  int e = blockIdx.x * 256 + threadIdx.x;
  if (e >= n_edges) return;
  const int src = eidx[e];
  const int tgt = eidx[n_edges + e];
  const int et = etype[e];
  const int pos = atomicAdd(&cursor[tgt], 1);
  packed[pos] = (unsigned int)src | ((unsigned int)et << 17);
}

// ===================== aggregate: one wave per node ========================
// out[n] = relu(h[n] + sum_{edges->n} (h[src] + emb[etype])), h in bf16
__global__ __launch_bounds__(256) void aggregate_kernel(
    const int* __restrict__ offsets, const unsigned int* __restrict__ packed,
    const float* __restrict__ eemb, const unsigned int* __restrict__ h2,
    float* __restrict__ out, int n_nodes) {
  const int gid = blockIdx.x * 256 + threadIdx.x;
  const int n = gid >> 6;
  const int lane = gid & 63;
  if (n >= n_nodes) return;

  const float2* e2 = (const float2*)eemb;

  const unsigned int sb = h2[n * 64 + lane];  // self (bf16x2)
  float ax = bf2f(sb & 0xffffu), ay = bf2f(sb >> 16);

  int j = offsets[n];
  const int end = offsets[n + 1];
  for (; j + 1 < end; j += 2) {  // 2-way unroll for MLP
    const unsigned int p0 = packed[j];
    const unsigned int p1 = packed[j + 1];
    const unsigned int g0 = h2[(p0 & 0x1FFFFu) * 64 + lane];
    const unsigned int g1 = h2[(p1 & 0x1FFFFu) * 64 + lane];
    const float2 e0 = e2[(p0 >> 17) * 64 + lane];
    const float2 e1 = e2[(p1 >> 17) * 64 + lane];
    ax += bf2f(g0 & 0xffffu) + e0.x + bf2f(g1 & 0xffffu) + e1.x;
    ay += bf2f(g0 >> 16) + e0.y + bf2f(g1 >> 16) + e1.y;
  }
  if (j < end) {
    const unsigned int p0 = packed[j];
    const unsigned int g0 = h2[(p0 & 0x1FFFFu) * 64 + lane];
    const float2 e0 = e2[(p0 >> 17) * 64 + lane];
    ax += bf2f(g0 & 0xffffu) + e0.x;
    ay += bf2f(g0 >> 16) + e0.y;
  }
  float2 r;
  r.x = fmaxf(ax, 0.f);
  r.y = fmaxf(ay, 0.f);
  ((float2*)out)[(size_t)n * 64 + lane] = r;
}

// ===========================================================================
extern "C" void kernel_launch(void* const* d_in, const int* in_sizes, int n_in,
                              void* d_out, int out_size, void* d_ws,
                              size_t ws_size, hipStream_t stream) {
  const float* nf   = (const float*)d_in[0];  // (N, 128) f32
  const int*   eidx = (const int*)d_in[1];    // (2, E) int
  const int*   etyp = (const int*)d_in[2];    // (E,) int
  const float* eemb = (const float*)d_in[3];  // (64, 128) f32
  const float* W    = (const float*)d_in[4];  // (128, 128) f32
  const float* b    = (const float*)d_in[5];  // (128,) f32

  const int n_nodes = in_sizes[0] / D;  // 100000
  const int n_edges = in_sizes[2];      // 625000

  float* out = (float*)d_out;

  // workspace layout (~29.5 MB); Wt first for 16B alignment of everything
  char* base = (char*)d_ws;
  unsigned short* Wt = (unsigned short*)base;                 // 32 KB
  unsigned short* h_bf = (unsigned short*)(base + 32768);     // N*128 bf16
  int* counts = (int*)(base + 32768 + (size_t)n_nodes * D * 2);
  int* offsets = counts + n_nodes;
  int* cursor = offsets + (n_nodes + 1);
  int* blockSums = cursor + n_nodes;
  int* blockOffs = blockSums + 1024;
  unsigned int* packed = (unsigned int*)(blockOffs + 1024);   // E uints

  const int nb = (n_nodes + 1023) / 1024;  // 98

  // 1) W transpose+cast (once per call; tiny)
  wt_prep_kernel<<<64, 256, 0, stream>>>(W, Wt);

  // 2) GEMM h_bf = bf16(nf @ W + b)
  gemm_h_kernel<<<(n_nodes + 31) / 32, 256, 0, stream>>>(nf, Wt, b, h_bf,
                                                         n_nodes);

  // 3) CSR build
  hipMemsetAsync(counts, 0, (size_t)n_nodes * 4, stream);
  hist_kernel<<<(n_edges + 255) / 256, 256, 0, stream>>>(eidx, counts, n_edges);
  scan1_kernel<<<nb, 256, 0, stream>>>(counts, offsets, blockSums, n_nodes);
  scan2_kernel<<<1, 1024, 0, stream>>>(blockSums, blockOffs, nb);
  scan3_kernel<<<nb, 256, 0, stream>>>(offsets, cursor, blockOffs, n_nodes,
                                       n_edges);
  scatter_kernel<<<(n_edges + 255) / 256, 256, 0, stream>>>(eidx, etyp, cursor,
                                                            packed, n_edges);

  // 4) aggregate + self + ReLU
  const long long aggThreads = (long long)n_nodes * 64;
  aggregate_kernel<<<(int)((aggThreads + 255) / 256), 256, 0, stream>>>(
      offsets, packed, eemb, (const unsigned int*)h_bf, out, n_nodes);
}

// Round 5
// 154.169 us; speedup vs baseline: 3.8278x; 1.0450x over previous
//
#include <hip/hip_runtime.h>
#include <hip/hip_bf16.h>

#define D 128  // D_IN == D_OUT == 128

typedef __attribute__((ext_vector_type(8))) short short8v;   // 8 bf16 (4 VGPR)
typedef __attribute__((ext_vector_type(4))) float float4v;   // MFMA acc

__device__ __forceinline__ unsigned short f2bf(float f) {
  union { float f; unsigned int u; } v; v.f = f;
  unsigned int r = v.u + 0x7fffu + ((v.u >> 16) & 1u);  // RNE
  return (unsigned short)(r >> 16);
}
__device__ __forceinline__ float bf2f(unsigned int bits16) {
  union { unsigned int u; float f; } v; v.u = bits16 << 16;
  return v.f;
}

// ================= prep: Wt[n][k] = bf16(W[k][n]); em_bf = bf16(eemb) =====
__global__ __launch_bounds__(256) void prep_kernel(
    const float* __restrict__ W, const float* __restrict__ eemb,
    unsigned short* __restrict__ Wt, unsigned short* __restrict__ em_bf) {
  int i = blockIdx.x * 256 + threadIdx.x;
  if (i < D * D) Wt[i] = f2bf(W[(i & 127) * D + (i >> 7)]);      // transpose
  if (i < 64 * D) em_bf[i] = f2bf(eemb[i]);
}

// ================= GEMM: h_bf = bf16(nf @ W + b) via swapped MFMA =========
// Block 256 = 4 waves; tile = 64 nodes x 128 cols.
// Swapped operands: mfma(A=Wt_frag, B=X_frag) -> D[row=h_col][col=node].
// Lane (m = l&15, q = l>>4) holds node (base+m), h-cols (q*4 .. q*4+3) per acc
// -> epilogue stores dwordx2 (4 bf16 = 8B contiguous) per acc register group.
#define XS_STRIDE 138  // bf16 elems; 69 dwords === 5 (mod 32) -> ~2-way banks
__global__ __launch_bounds__(256) void gemm_h_kernel(
    const float* __restrict__ nf, const unsigned short* __restrict__ Wt,
    const float* __restrict__ b, unsigned short* __restrict__ h_bf,
    int n_nodes) {
  __shared__ unsigned short Xs[64 * XS_STRIDE];  // 17.6 KB
  const int tid = threadIdx.x;
  const int nodeBase = blockIdx.x * 64;

  // ---- stage X tile (64x128 f32 -> bf16 LDS), coalesced, tail-guarded ----
  #pragma unroll
  for (int s = 0; s < 4; ++s) {
    const int row = (tid >> 4) + s * 16;
    const int col = (tid & 15) * 8;
    short8v sv;
    if (nodeBase + row < n_nodes) {
      const float4* p = (const float4*)&nf[(size_t)(nodeBase + row) * D + col];
      float4 a = p[0], c = p[1];
      sv[0] = (short)f2bf(a.x); sv[1] = (short)f2bf(a.y);
      sv[2] = (short)f2bf(a.z); sv[3] = (short)f2bf(a.w);
      sv[4] = (short)f2bf(c.x); sv[5] = (short)f2bf(c.y);
      sv[6] = (short)f2bf(c.z); sv[7] = (short)f2bf(c.w);
    } else {
      sv = short8v{0, 0, 0, 0, 0, 0, 0, 0};
    }
    *(short8v*)&Xs[row * XS_STRIDE + col] = sv;
  }

  const int w = tid >> 6;
  const int l = tid & 63;
  const int m = l & 15;    // A row (h col) / B col (node) within 16-tile
  const int q = l >> 4;    // k-quarter; D rows q*4..q*4+3
  const int n0 = (w & 1) * 64;        // h-col half for this wave
  const int nodeHalf = (w >> 1) * 32; // node half for this wave

  // ---- A fragments (Wt rows = h cols) hoisted from L2-hot global ----
  short8v afrag[4][4];  // [n-tile][k-chunk]
  #pragma unroll
  for (int nt = 0; nt < 4; ++nt) {
    const int n = n0 + nt * 16 + m;
    #pragma unroll
    for (int kc = 0; kc < 4; ++kc)
      afrag[nt][kc] = *(const short8v*)&Wt[n * D + kc * 32 + q * 8];
  }

  float4v acc[4][2] = {};
  __syncthreads();

  #pragma unroll
  for (int kc = 0; kc < 4; ++kc) {
    #pragma unroll
    for (int t = 0; t < 2; ++t) {
      const int node = nodeHalf + t * 16 + m;
      const short8v bv =
          *(const short8v*)&Xs[node * XS_STRIDE + kc * 32 + q * 8];
      #pragma unroll
      for (int nt = 0; nt < 4; ++nt)
        acc[nt][t] = __builtin_amdgcn_mfma_f32_16x16x32_bf16(
            afrag[nt][kc], bv, acc[nt][t], 0, 0, 0);
    }
  }

  // ---- epilogue: +bias, pack 4 bf16, one dwordx2 store per acc group ----
  #pragma unroll
  for (int nt = 0; nt < 4; ++nt) {
    const int colBase = n0 + nt * 16 + q * 4;
    const float4 bv = *(const float4*)&b[colBase];
    #pragma unroll
    for (int t = 0; t < 2; ++t) {
      const int node = nodeBase + nodeHalf + t * 16 + m;
      if (node < n_nodes) {
        const unsigned int lo = (unsigned int)f2bf(acc[nt][t][0] + bv.x) |
                                ((unsigned int)f2bf(acc[nt][t][1] + bv.y) << 16);
        const unsigned int hi = (unsigned int)f2bf(acc[nt][t][2] + bv.z) |
                                ((unsigned int)f2bf(acc[nt][t][3] + bv.w) << 16);
        uint2 val; val.x = lo; val.y = hi;
        *(uint2*)&h_bf[(size_t)node * D + colBase] = val;
      }
    }
  }
}

// ============================ CSR build ====================================
__global__ __launch_bounds__(256) void hist_kernel(
    const int* __restrict__ eidx, int* __restrict__ counts, int n_edges) {
  int e = blockIdx.x * 256 + threadIdx.x;
  if (e < n_edges) atomicAdd(&counts[eidx[n_edges + e]], 1);
}

__global__ __launch_bounds__(256) void scan1_kernel(
    const int* __restrict__ counts, int* __restrict__ offsets,
    int* __restrict__ blockSums, int n) {
  __shared__ int lds[256];
  const int tid = threadIdx.x;
  const int base = blockIdx.x * 1024 + tid * 4;
  int v[4];
  #pragma unroll
  for (int k = 0; k < 4; ++k) v[k] = (base + k < n) ? counts[base + k] : 0;
  int s = v[0] + v[1] + v[2] + v[3];
  lds[tid] = s;
  for (int off = 1; off < 256; off <<= 1) {
    __syncthreads();
    int t = (tid >= off) ? lds[tid - off] : 0;
    __syncthreads();
    lds[tid] += t;
  }
  __syncthreads();
  int run = lds[tid] - s;
  #pragma unroll
  for (int k = 0; k < 4; ++k) {
    if (base + k < n) offsets[base + k] = run;
    run += v[k];
  }
  if (tid == 255) blockSums[blockIdx.x] = lds[255];
}

__global__ __launch_bounds__(1024) void scan2_kernel(int* __restrict__ blockSums,
                                                     int* __restrict__ blockOffs,
                                                     int nb) {
  __shared__ int lds[1024];
  const int tid = threadIdx.x;
  int v = (tid < nb) ? blockSums[tid] : 0;
  lds[tid] = v;
  for (int off = 1; off < 1024; off <<= 1) {
    __syncthreads();
    int t = (tid >= off) ? lds[tid - off] : 0;
    __syncthreads();
    lds[tid] += t;
  }
  __syncthreads();
  if (tid < nb) blockOffs[tid] = lds[tid] - v;
}

__global__ __launch_bounds__(256) void scan3_kernel(
    int* __restrict__ offsets, int* __restrict__ cursor,
    const int* __restrict__ blockOffs, int n, int n_edges) {
  const int tid = threadIdx.x;
  const int add = blockOffs[blockIdx.x];
  const int base = blockIdx.x * 1024 + tid * 4;
  #pragma unroll
  for (int k = 0; k < 4; ++k) {
    int i = base + k;
    if (i < n) {
      int o = offsets[i] + add;
      offsets[i] = o;
      cursor[i] = o;
    }
  }
  if (blockIdx.x == 0 && tid == 0) offsets[n] = n_edges;
}

__global__ __launch_bounds__(256) void scatter_kernel(
    const int* __restrict__ eidx, const int* __restrict__ etype,
    int* __restrict__ cursor, unsigned int* __restrict__ packed, int n_edges) {
  int e = blockIdx.x * 256 + threadIdx.x;
  if (e >= n_edges) return;
  const int src = eidx[e];
  const int tgt = eidx[n_edges + e];
  const int et = etype[e];
  const int pos = atomicAdd(&cursor[tgt], 1);
  packed[pos] = (unsigned int)src | ((unsigned int)et << 17);
}

// ===================== aggregate: one wave per node ========================
// out[n] = relu(h[n] + sum_{edges->n} (h[src] + emb[etype])), h & emb in bf16
// 4-deep gather pipeline (8 independent loads in flight) for MLP.
__global__ __launch_bounds__(256) void aggregate_kernel(
    const int* __restrict__ offsets, const unsigned int* __restrict__ packed,
    const unsigned int* __restrict__ em, const unsigned int* __restrict__ h2,
    float* __restrict__ out, int n_nodes) {
  const int gid = blockIdx.x * 256 + threadIdx.x;
  const int n = gid >> 6;
  const int lane = gid & 63;
  if (n >= n_nodes) return;

  const unsigned int sb = h2[n * 64 + lane];  // self (bf16x2)
  float ax0 = bf2f(sb & 0xffffu), ay0 = bf2f(sb >> 16);
  float ax1 = 0.f, ay1 = 0.f;

  int j = offsets[n];
  const int end = offsets[n + 1];
  for (; j + 3 < end; j += 4) {
    const unsigned int p0 = packed[j];
    const unsigned int p1 = packed[j + 1];
    const unsigned int p2 = packed[j + 2];
    const unsigned int p3 = packed[j + 3];
    const unsigned int g0 = h2[(p0 & 0x1FFFFu) * 64 + lane];
    const unsigned int g1 = h2[(p1 & 0x1FFFFu) * 64 + lane];
    const unsigned int g2 = h2[(p2 & 0x1FFFFu) * 64 + lane];
    const unsigned int g3 = h2[(p3 & 0x1FFFFu) * 64 + lane];
    const unsigned int e0 = em[(p0 >> 17) * 64 + lane];
    const unsigned int e1 = em[(p1 >> 17) * 64 + lane];
    const unsigned int e2 = em[(p2 >> 17) * 64 + lane];
    const unsigned int e3 = em[(p3 >> 17) * 64 + lane];
    ax0 += bf2f(g0 & 0xffffu) + bf2f(e0 & 0xffffu);
    ay0 += bf2f(g0 >> 16) + bf2f(e0 >> 16);
    ax1 += bf2f(g1 & 0xffffu) + bf2f(e1 & 0xffffu);
    ay1 += bf2f(g1 >> 16) + bf2f(e1 >> 16);
    ax0 += bf2f(g2 & 0xffffu) + bf2f(e2 & 0xffffu);
    ay0 += bf2f(g2 >> 16) + bf2f(e2 >> 16);
    ax1 += bf2f(g3 & 0xffffu) + bf2f(e3 & 0xffffu);
    ay1 += bf2f(g3 >> 16) + bf2f(e3 >> 16);
  }
  for (; j < end; ++j) {
    const unsigned int p0 = packed[j];
    const unsigned int g0 = h2[(p0 & 0x1FFFFu) * 64 + lane];
    const unsigned int e0 = em[(p0 >> 17) * 64 + lane];
    ax0 += bf2f(g0 & 0xffffu) + bf2f(e0 & 0xffffu);
    ay0 += bf2f(g0 >> 16) + bf2f(e0 >> 16);
  }
  float2 r;
  r.x = fmaxf(ax0 + ax1, 0.f);
  r.y = fmaxf(ay0 + ay1, 0.f);
  ((float2*)out)[(size_t)n * 64 + lane] = r;
}

// ===========================================================================
extern "C" void kernel_launch(void* const* d_in, const int* in_sizes, int n_in,
                              void* d_out, int out_size, void* d_ws,
                              size_t ws_size, hipStream_t stream) {
  const float* nf   = (const float*)d_in[0];  // (N, 128) f32
  const int*   eidx = (const int*)d_in[1];    // (2, E) int
  const int*   etyp = (const int*)d_in[2];    // (E,) int
  const float* eemb = (const float*)d_in[3];  // (64, 128) f32
  const float* W    = (const float*)d_in[4];  // (128, 128) f32
  const float* b    = (const float*)d_in[5];  // (128,) f32

  const int n_nodes = in_sizes[0] / D;  // 100000
  const int n_edges = in_sizes[2];      // 625000

  float* out = (float*)d_out;

  // workspace layout (~29.6 MB); 16B alignment maintained
  char* base = (char*)d_ws;
  unsigned short* Wt = (unsigned short*)base;                  // 32 KB
  unsigned short* em_bf = (unsigned short*)(base + 32768);     // 16 KB
  unsigned short* h_bf = (unsigned short*)(base + 49152);      // N*128 bf16
  int* counts = (int*)(base + 49152 + (size_t)n_nodes * D * 2);
  int* offsets = counts + n_nodes;
  int* cursor = offsets + (n_nodes + 1);
  int* blockSums = cursor + n_nodes;
  int* blockOffs = blockSums + 1024;
  unsigned int* packed = (unsigned int*)(blockOffs + 1024);    // E uints

  const int nb = (n_nodes + 1023) / 1024;  // 98

  // 1) W transpose+cast, eemb cast (tiny)
  prep_kernel<<<64, 256, 0, stream>>>(W, eemb, Wt, em_bf);

  // 2) GEMM h_bf = bf16(nf @ W + b), 64-node tiles
  gemm_h_kernel<<<(n_nodes + 63) / 64, 256, 0, stream>>>(nf, Wt, b, h_bf,
                                                         n_nodes);

  // 3) CSR build
  (void)hipMemsetAsync(counts, 0, (size_t)n_nodes * 4, stream);
  hist_kernel<<<(n_edges + 255) / 256, 256, 0, stream>>>(eidx, counts, n_edges);
  scan1_kernel<<<nb, 256, 0, stream>>>(counts, offsets, blockSums, n_nodes);
  scan2_kernel<<<1, 1024, 0, stream>>>(blockSums, blockOffs, nb);
  scan3_kernel<<<nb, 256, 0, stream>>>(offsets, cursor, blockOffs, n_nodes,
                                       n_edges);
  scatter_kernel<<<(n_edges + 255) / 256, 256, 0, stream>>>(eidx, etyp, cursor,
                                                            packed, n_edges);

  // 4) aggregate + self + ReLU
  const long long aggThreads = (long long)n_nodes * 64;
  aggregate_kernel<<<(int)((aggThreads + 255) / 256), 256, 0, stream>>>(
      offsets, packed, (const unsigned int*)em_bf, (const unsigned int*)h_bf,
      out, n_nodes);
}

// Round 6
// 148.107 us; speedup vs baseline: 3.9845x; 1.0409x over previous
//
#include <hip/hip_runtime.h>
#include <hip/hip_bf16.h>

#define D 128  // D_IN == D_OUT == 128

typedef __attribute__((ext_vector_type(8))) short short8v;   // 8 bf16 (4 VGPR)
typedef __attribute__((ext_vector_type(4))) float float4v;   // MFMA acc

__device__ __forceinline__ unsigned short f2bf(float f) {
  union { float f; unsigned int u; } v; v.f = f;
  unsigned int r = v.u + 0x7fffu + ((v.u >> 16) & 1u);  // RNE
  return (unsigned short)(r >> 16);
}
// packed pair conversion -> compiler emits v_cvt_pk_bf16_f32 (RNE)
__device__ __forceinline__ unsigned int pkbf(float lo, float hi) {
  float2 f; f.x = lo; f.y = hi;
  __hip_bfloat162 v = __float22bfloat162_rn(f);
  union { __hip_bfloat162 b; unsigned int u; } c; c.b = v;
  return c.u;
}
__device__ __forceinline__ float bflo(unsigned int u) {
  union { unsigned int v; float f; } c; c.v = u << 16; return c.f;
}
__device__ __forceinline__ float bfhi(unsigned int u) {
  union { unsigned int v; float f; } c; c.v = u & 0xffff0000u; return c.f;
}

// ====== prep: Wt[n][k]=bf16(W[k][n]); em_bf=bf16(eemb); zero rows =========
__global__ __launch_bounds__(256) void prep_kernel(
    const float* __restrict__ W, const float* __restrict__ eemb,
    unsigned short* __restrict__ Wt, unsigned short* __restrict__ em_bf,
    unsigned short* __restrict__ h_bf, int n_nodes) {
  int i = blockIdx.x * 256 + threadIdx.x;
  if (i < D * D) Wt[i] = f2bf(W[(i & 127) * D + (i >> 7)]);      // transpose
  if (i < 64 * D) em_bf[i] = f2bf(eemb[i]);
  // zero rows for predicated-gather sentinel
  if (i < 64) ((unsigned int*)(h_bf + (size_t)n_nodes * D))[i] = 0u;
  if (i >= 64 && i < 128) ((unsigned int*)(em_bf + 64 * D))[i - 64] = 0u;
}

// ================= GEMM: h_bf = bf16(nf @ W + b) via swapped MFMA =========
// Block 256 = 4 waves; tile = 64 nodes x 128 cols.
// mfma(A=Wt_frag, B=X_frag) -> D[row=h_col][col=node]; lane holds one node's
// 4 consecutive h-cols per acc group -> 8B stores.
#define XS_STRIDE 138  // bf16 elems; 69 dwords === 5 (mod 32) -> spread banks
__global__ __launch_bounds__(256) void gemm_h_kernel(
    const float* __restrict__ nf, const unsigned short* __restrict__ Wt,
    const float* __restrict__ b, unsigned short* __restrict__ h_bf,
    int n_nodes) {
  __shared__ unsigned short Xs[64 * XS_STRIDE];  // 17.6 KB
  const int tid = threadIdx.x;
  const int nodeBase = blockIdx.x * 64;

  // ---- stage X tile (64x128 f32 -> bf16 LDS) via cvt_pk ----
  #pragma unroll
  for (int s = 0; s < 4; ++s) {
    const int row = (tid >> 4) + s * 16;
    const int col = (tid & 15) * 8;
    uint4 sv = {0u, 0u, 0u, 0u};
    if (nodeBase + row < n_nodes) {
      const float4* p = (const float4*)&nf[(size_t)(nodeBase + row) * D + col];
      float4 a = p[0], c = p[1];
      sv.x = pkbf(a.x, a.y);
      sv.y = pkbf(a.z, a.w);
      sv.z = pkbf(c.x, c.y);
      sv.w = pkbf(c.z, c.w);
    }
    *(uint4*)&Xs[row * XS_STRIDE + col] = sv;
  }

  const int w = tid >> 6;
  const int l = tid & 63;
  const int m = l & 15;
  const int q = l >> 4;
  const int n0 = (w & 1) * 64;        // h-col half for this wave
  const int nodeHalf = (w >> 1) * 32; // node half for this wave

  // ---- A fragments (Wt rows = h cols) from L2-hot global ----
  short8v afrag[4][4];  // [n-tile][k-chunk]
  #pragma unroll
  for (int nt = 0; nt < 4; ++nt) {
    const int n = n0 + nt * 16 + m;
    #pragma unroll
    for (int kc = 0; kc < 4; ++kc)
      afrag[nt][kc] = *(const short8v*)&Wt[n * D + kc * 32 + q * 8];
  }

  float4v acc[4][2] = {};
  __syncthreads();

  #pragma unroll
  for (int kc = 0; kc < 4; ++kc) {
    #pragma unroll
    for (int t = 0; t < 2; ++t) {
      const int node = nodeHalf + t * 16 + m;
      const short8v bv =
          *(const short8v*)&Xs[node * XS_STRIDE + kc * 32 + q * 8];
      #pragma unroll
      for (int nt = 0; nt < 4; ++nt)
        acc[nt][t] = __builtin_amdgcn_mfma_f32_16x16x32_bf16(
            afrag[nt][kc], bv, acc[nt][t], 0, 0, 0);
    }
  }

  // ---- epilogue: +bias, cvt_pk, 8B stores ----
  #pragma unroll
  for (int nt = 0; nt < 4; ++nt) {
    const int colBase = n0 + nt * 16 + q * 4;
    const float4 bv = *(const float4*)&b[colBase];
    #pragma unroll
    for (int t = 0; t < 2; ++t) {
      const int node = nodeBase + nodeHalf + t * 16 + m;
      if (node < n_nodes) {
        uint2 val;
        val.x = pkbf(acc[nt][t][0] + bv.x, acc[nt][t][1] + bv.y);
        val.y = pkbf(acc[nt][t][2] + bv.z, acc[nt][t][3] + bv.w);
        *(uint2*)&h_bf[(size_t)node * D + colBase] = val;
      }
    }
  }
}

// ============================ CSR build ====================================
__global__ __launch_bounds__(256) void hist_kernel(
    const int* __restrict__ eidx, int* __restrict__ counts, int n_edges) {
  int e = blockIdx.x * 256 + threadIdx.x;
  if (e < n_edges) atomicAdd(&counts[eidx[n_edges + e]], 1);
}

__global__ __launch_bounds__(256) void scan1_kernel(
    const int* __restrict__ counts, int* __restrict__ offsets,
    int* __restrict__ blockSums, int n) {
  __shared__ int lds[256];
  const int tid = threadIdx.x;
  const int base = blockIdx.x * 1024 + tid * 4;
  int v[4];
  #pragma unroll
  for (int k = 0; k < 4; ++k) v[k] = (base + k < n) ? counts[base + k] : 0;
  int s = v[0] + v[1] + v[2] + v[3];
  lds[tid] = s;
  for (int off = 1; off < 256; off <<= 1) {
    __syncthreads();
    int t = (tid >= off) ? lds[tid - off] : 0;
    __syncthreads();
    lds[tid] += t;
  }
  __syncthreads();
  int run = lds[tid] - s;
  #pragma unroll
  for (int k = 0; k < 4; ++k) {
    if (base + k < n) offsets[base + k] = run;
    run += v[k];
  }
  if (tid == 255) blockSums[blockIdx.x] = lds[255];
}

__global__ __launch_bounds__(1024) void scan2_kernel(int* __restrict__ blockSums,
                                                     int* __restrict__ blockOffs,
                                                     int nb) {
  __shared__ int lds[1024];
  const int tid = threadIdx.x;
  int v = (tid < nb) ? blockSums[tid] : 0;
  lds[tid] = v;
  for (int off = 1; off < 1024; off <<= 1) {
    __syncthreads();
    int t = (tid >= off) ? lds[tid - off] : 0;
    __syncthreads();
    lds[tid] += t;
  }
  __syncthreads();
  if (tid < nb) blockOffs[tid] = lds[tid] - v;
}

__global__ __launch_bounds__(256) void scan3_kernel(
    int* __restrict__ offsets, int* __restrict__ cursor,
    const int* __restrict__ blockOffs, int n, int n_edges) {
  const int tid = threadIdx.x;
  const int add = blockOffs[blockIdx.x];
  const int base = blockIdx.x * 1024 + tid * 4;
  #pragma unroll
  for (int k = 0; k < 4; ++k) {
    int i = base + k;
    if (i < n) {
      int o = offsets[i] + add;
      offsets[i] = o;
      cursor[i] = o;
    }
  }
  if (blockIdx.x == 0 && tid == 0) offsets[n] = n_edges;
}

__global__ __launch_bounds__(256) void scatter_kernel(
    const int* __restrict__ eidx, const int* __restrict__ etype,
    int* __restrict__ cursor, unsigned int* __restrict__ packed, int n_edges) {
  int e = blockIdx.x * 256 + threadIdx.x;
  if (e >= n_edges) return;
  const int src = eidx[e];
  const int tgt = eidx[n_edges + e];
  const int et = etype[e];
  const int pos = atomicAdd(&cursor[tgt], 1);
  packed[pos] = (unsigned int)src | ((unsigned int)et << 17);
}

// ================ aggregate: 2 nodes per wave (32 lanes each) ==============
// out[n] = relu(h[n] + sum_{edges->n} (h[src] + em[etype])); h,em bf16.
// Lane covers 4 dims via uint2 (8B); invalid edges -> zero rows (predicated).
__global__ __launch_bounds__(256) void aggregate_kernel(
    const int* __restrict__ offsets, const unsigned int* __restrict__ packed,
    const uint2* __restrict__ e4, const uint2* __restrict__ h4,
    float* __restrict__ out, int n_nodes, int n_edges, unsigned int zero_p) {
  const int gid = blockIdx.x * 256 + threadIdx.x;
  const int lane = threadIdx.x & 63;
  const int half = lane >> 5;
  const int sl = lane & 31;
  const int n = (gid >> 6) * 2 + half;
  if (n >= n_nodes) return;

  const uint2 sb = h4[(size_t)n * 32 + sl];  // self (4 bf16)
  float a0 = bflo(sb.x), a1 = bfhi(sb.x), a2 = bflo(sb.y), a3 = bfhi(sb.y);
  float c0 = 0.f, c1 = 0.f, c2 = 0.f, c3 = 0.f;

  int j = offsets[n];
  const int end = offsets[n + 1];
  int trips = (end - j + 3) >> 2;
  int to = __shfl_xor(trips, 32);
  const int T = trips > to ? trips : to;
  const int emax = n_edges - 1;

  for (int t = 0; t < T; ++t, j += 4) {
    const int j1 = j + 1, j2 = j + 2, j3 = j + 3;
    unsigned int p0 = packed[j  <= emax ? j  : emax];
    unsigned int p1 = packed[j1 <= emax ? j1 : emax];
    unsigned int p2 = packed[j2 <= emax ? j2 : emax];
    unsigned int p3 = packed[j3 <= emax ? j3 : emax];
    p0 = (j  < end) ? p0 : zero_p;
    p1 = (j1 < end) ? p1 : zero_p;
    p2 = (j2 < end) ? p2 : zero_p;
    p3 = (j3 < end) ? p3 : zero_p;
    const uint2 g0 = h4[(size_t)(p0 & 0x1FFFFu) * 32 + sl];
    const uint2 g1 = h4[(size_t)(p1 & 0x1FFFFu) * 32 + sl];
    const uint2 g2 = h4[(size_t)(p2 & 0x1FFFFu) * 32 + sl];
    const uint2 g3 = h4[(size_t)(p3 & 0x1FFFFu) * 32 + sl];
    const uint2 e0 = e4[(p0 >> 17) * 32 + sl];
    const uint2 e1 = e4[(p1 >> 17) * 32 + sl];
    const uint2 e2 = e4[(p2 >> 17) * 32 + sl];
    const uint2 e3 = e4[(p3 >> 17) * 32 + sl];
    a0 += bflo(g0.x) + bflo(e0.x); a1 += bfhi(g0.x) + bfhi(e0.x);
    a2 += bflo(g0.y) + bflo(e0.y); a3 += bfhi(g0.y) + bfhi(e0.y);
    c0 += bflo(g1.x) + bflo(e1.x); c1 += bfhi(g1.x) + bfhi(e1.x);
    c2 += bflo(g1.y) + bflo(e1.y); c3 += bfhi(g1.y) + bfhi(e1.y);
    a0 += bflo(g2.x) + bflo(e2.x); a1 += bfhi(g2.x) + bfhi(e2.x);
    a2 += bflo(g2.y) + bflo(e2.y); a3 += bfhi(g2.y) + bfhi(e2.y);
    c0 += bflo(g3.x) + bflo(e3.x); c1 += bfhi(g3.x) + bfhi(e3.x);
    c2 += bflo(g3.y) + bflo(e3.y); c3 += bfhi(g3.y) + bfhi(e3.y);
  }

  float4 r;
  r.x = fmaxf(a0 + c0, 0.f);
  r.y = fmaxf(a1 + c1, 0.f);
  r.z = fmaxf(a2 + c2, 0.f);
  r.w = fmaxf(a3 + c3, 0.f);
  ((float4*)out)[(size_t)n * 32 + sl] = r;
}

// ===========================================================================
extern "C" void kernel_launch(void* const* d_in, const int* in_sizes, int n_in,
                              void* d_out, int out_size, void* d_ws,
                              size_t ws_size, hipStream_t stream) {
  const float* nf   = (const float*)d_in[0];  // (N, 128) f32
  const int*   eidx = (const int*)d_in[1];    // (2, E) int
  const int*   etyp = (const int*)d_in[2];    // (E,) int
  const float* eemb = (const float*)d_in[3];  // (64, 128) f32
  const float* W    = (const float*)d_in[4];  // (128, 128) f32
  const float* b    = (const float*)d_in[5];  // (128,) f32

  const int n_nodes = in_sizes[0] / D;  // 100000
  const int n_edges = in_sizes[2];      // 625000

  float* out = (float*)d_out;

  // workspace layout (~29.5 MB); 16B alignment maintained
  char* base = (char*)d_ws;
  unsigned short* Wt = (unsigned short*)base;                  // 32 KB
  unsigned short* em_bf = (unsigned short*)(base + 32768);     // 65 rows
  unsigned short* h_bf = (unsigned short*)(base + 65536);      // (N+1)*128 bf16
  char* tail = base + 65536 + (size_t)(n_nodes + 1) * D * 2;
  int* counts = (int*)tail;
  int* offsets = counts + n_nodes;
  int* cursor = offsets + (n_nodes + 1);
  int* blockSums = cursor + n_nodes;
  int* blockOffs = blockSums + 1024;
  unsigned int* packed = (unsigned int*)(blockOffs + 1024);    // E uints

  const int nb = (n_nodes + 1023) / 1024;  // 98

  // 1) W transpose+cast, eemb cast, zero sentinel rows
  prep_kernel<<<64, 256, 0, stream>>>(W, eemb, Wt, em_bf, h_bf, n_nodes);

  // 2) GEMM h_bf = bf16(nf @ W + b), 64-node tiles
  gemm_h_kernel<<<(n_nodes + 63) / 64, 256, 0, stream>>>(nf, Wt, b, h_bf,
                                                         n_nodes);

  // 3) CSR build
  (void)hipMemsetAsync(counts, 0, (size_t)n_nodes * 4, stream);
  hist_kernel<<<(n_edges + 255) / 256, 256, 0, stream>>>(eidx, counts, n_edges);
  scan1_kernel<<<nb, 256, 0, stream>>>(counts, offsets, blockSums, n_nodes);
  scan2_kernel<<<1, 1024, 0, stream>>>(blockSums, blockOffs, nb);
  scan3_kernel<<<nb, 256, 0, stream>>>(offsets, cursor, blockOffs, n_nodes,
                                       n_edges);
  scatter_kernel<<<(n_edges + 255) / 256, 256, 0, stream>>>(eidx, etyp, cursor,
                                                            packed, n_edges);

  // 4) aggregate + self + ReLU (2 nodes/wave)
  const unsigned int zero_p = (unsigned int)n_nodes | (64u << 17);
  const int aggBlocks = (n_nodes + 7) / 8;  // 8 nodes per 256-thread block
  aggregate_kernel<<<aggBlocks, 256, 0, stream>>>(
      offsets, packed, (const uint2*)em_bf, (const uint2*)h_bf, out, n_nodes,
      n_edges, zero_p);
}

// Round 7
// 143.296 us; speedup vs baseline: 4.1183x; 1.0336x over previous
//
#include <hip/hip_runtime.h>
#include <hip/hip_bf16.h>

#define D 128  // D_IN == D_OUT == 128

typedef __attribute__((ext_vector_type(8))) short short8v;   // 8 bf16 (4 VGPR)
typedef __attribute__((ext_vector_type(4))) float float4v;   // MFMA acc

__device__ __forceinline__ unsigned short f2bf(float f) {
  union { float f; unsigned int u; } v; v.f = f;
  unsigned int r = v.u + 0x7fffu + ((v.u >> 16) & 1u);  // RNE
  return (unsigned short)(r >> 16);
}
// packed pair conversion -> v_cvt_pk_bf16_f32 (RNE)
__device__ __forceinline__ unsigned int pkbf(float lo, float hi) {
  float2 f; f.x = lo; f.y = hi;
  __hip_bfloat162 v = __float22bfloat162_rn(f);
  union { __hip_bfloat162 b; unsigned int u; } c; c.b = v;
  return c.u;
}
__device__ __forceinline__ float bflo(unsigned int u) {
  union { unsigned int v; float f; } c; c.v = u << 16; return c.f;
}
__device__ __forceinline__ float bfhi(unsigned int u) {
  union { unsigned int v; float f; } c; c.v = u & 0xffff0000u; return c.f;
}

// == prep: Wt[n][k]=bf16(W[k][n]); em_bf=bf16(eemb); zero counts+sentinels ==
__global__ __launch_bounds__(256) void prep_kernel(
    const float* __restrict__ W, const float* __restrict__ eemb,
    unsigned short* __restrict__ Wt, unsigned short* __restrict__ em_bf,
    unsigned short* __restrict__ h_bf, int* __restrict__ counts,
    int n_nodes) {
  int i = blockIdx.x * 256 + threadIdx.x;
  if (i < D * D) Wt[i] = f2bf(W[(i & 127) * D + (i >> 7)]);      // transpose
  if (i < 64 * D) em_bf[i] = f2bf(eemb[i]);
  if (i < 64) ((unsigned int*)(h_bf + (size_t)n_nodes * D))[i] = 0u;
  if (i >= 64 && i < 128) ((unsigned int*)(em_bf + 64 * D))[i - 64] = 0u;
  if (i < n_nodes) counts[i] = 0;  // replaces hipMemsetAsync
}

// ======== GEMM (swapped MFMA) + fused edge histogram chunk ================
// Block 256 = 4 waves; tile = 64 nodes x 128 cols.
// mfma(A=Wt_frag, B=X_frag) -> D[row=h_col][col=node]; lane holds one node's
// 4 consecutive h-cols per acc group -> 8B stores. Then the block histograms
// its 400-edge chunk (atomics hide under other blocks' compute).
#define XS_STRIDE 138  // bf16 elems; 69 dwords === 5 (mod 32) -> spread banks
__global__ __launch_bounds__(256) void gemm_h_kernel(
    const float* __restrict__ nf, const unsigned short* __restrict__ Wt,
    const float* __restrict__ b, unsigned short* __restrict__ h_bf,
    const int* __restrict__ eidx_tgt, int* __restrict__ counts,
    int n_nodes, int n_edges, int epb) {
  __shared__ unsigned short Xs[64 * XS_STRIDE];  // 17.6 KB
  const int tid = threadIdx.x;
  const int nodeBase = blockIdx.x * 64;

  // ---- stage X tile (64x128 f32 -> bf16 LDS) via cvt_pk ----
  #pragma unroll
  for (int s = 0; s < 4; ++s) {
    const int row = (tid >> 4) + s * 16;
    const int col = (tid & 15) * 8;
    uint4 sv = {0u, 0u, 0u, 0u};
    if (nodeBase + row < n_nodes) {
      const float4* p = (const float4*)&nf[(size_t)(nodeBase + row) * D + col];
      float4 a = p[0], c = p[1];
      sv.x = pkbf(a.x, a.y);
      sv.y = pkbf(a.z, a.w);
      sv.z = pkbf(c.x, c.y);
      sv.w = pkbf(c.z, c.w);
    }
    *(uint4*)&Xs[row * XS_STRIDE + col] = sv;
  }

  const int w = tid >> 6;
  const int l = tid & 63;
  const int m = l & 15;
  const int q = l >> 4;
  const int n0 = (w & 1) * 64;        // h-col half for this wave
  const int nodeHalf = (w >> 1) * 32; // node half for this wave

  // ---- A fragments (Wt rows = h cols) from L2-hot global ----
  short8v afrag[4][4];  // [n-tile][k-chunk]
  #pragma unroll
  for (int nt = 0; nt < 4; ++nt) {
    const int n = n0 + nt * 16 + m;
    #pragma unroll
    for (int kc = 0; kc < 4; ++kc)
      afrag[nt][kc] = *(const short8v*)&Wt[n * D + kc * 32 + q * 8];
  }

  float4v acc[4][2] = {};
  __syncthreads();

  #pragma unroll
  for (int kc = 0; kc < 4; ++kc) {
    #pragma unroll
    for (int t = 0; t < 2; ++t) {
      const int node = nodeHalf + t * 16 + m;
      const short8v bv =
          *(const short8v*)&Xs[node * XS_STRIDE + kc * 32 + q * 8];
      #pragma unroll
      for (int nt = 0; nt < 4; ++nt)
        acc[nt][t] = __builtin_amdgcn_mfma_f32_16x16x32_bf16(
            afrag[nt][kc], bv, acc[nt][t], 0, 0, 0);
    }
  }

  // ---- epilogue: +bias, cvt_pk, 8B stores ----
  #pragma unroll
  for (int nt = 0; nt < 4; ++nt) {
    const int colBase = n0 + nt * 16 + q * 4;
    const float4 bv = *(const float4*)&b[colBase];
    #pragma unroll
    for (int t = 0; t < 2; ++t) {
      const int node = nodeBase + nodeHalf + t * 16 + m;
      if (node < n_nodes) {
        uint2 val;
        val.x = pkbf(acc[nt][t][0] + bv.x, acc[nt][t][1] + bv.y);
        val.y = pkbf(acc[nt][t][2] + bv.z, acc[nt][t][3] + bv.w);
        *(uint2*)&h_bf[(size_t)node * D + colBase] = val;
      }
    }
  }

  // ---- fused histogram: this block's edge chunk ----
  const int ebase = blockIdx.x * epb;
  int eend = ebase + epb;
  if (eend > n_edges) eend = n_edges;
  for (int e = ebase + tid; e < eend; e += 256)
    atomicAdd(&counts[eidx_tgt[e]], 1);
}

// ============================ scan =========================================
// pass 1: per-block (1024 elems) local exclusive scan; blockSums[b] = total
__global__ __launch_bounds__(256) void scan1_kernel(
    const int* __restrict__ counts, int* __restrict__ offsets,
    int* __restrict__ blockSums, int n) {
  __shared__ int lds[256];
  const int tid = threadIdx.x;
  const int base = blockIdx.x * 1024 + tid * 4;
  int v[4];
  #pragma unroll
  for (int k = 0; k < 4; ++k) v[k] = (base + k < n) ? counts[base + k] : 0;
  int s = v[0] + v[1] + v[2] + v[3];
  lds[tid] = s;
  for (int off = 1; off < 256; off <<= 1) {
    __syncthreads();
    int t = (tid >= off) ? lds[tid - off] : 0;
    __syncthreads();
    lds[tid] += t;
  }
  __syncthreads();
  int run = lds[tid] - s;
  #pragma unroll
  for (int k = 0; k < 4; ++k) {
    if (base + k < n) offsets[base + k] = run;
    run += v[k];
  }
  if (tid == 255) blockSums[blockIdx.x] = lds[255];
}

// pass 2 (fused scan2+scan3): each block reduces blockSums[0..bid-1] in LDS,
// adds to its 1024 offsets, copies to cursor. Requires nb <= 256.
__global__ __launch_bounds__(256) void scan23_kernel(
    int* __restrict__ offsets, int* __restrict__ cursor,
    const int* __restrict__ blockSums, int nb, int n, int n_edges) {
  __shared__ int lds[256];
  const int tid = threadIdx.x;
  const int bid = blockIdx.x;
  lds[tid] = (tid < bid && tid < nb) ? blockSums[tid] : 0;
  __syncthreads();
  #pragma unroll
  for (int off = 128; off > 0; off >>= 1) {
    if (tid < off) lds[tid] += lds[tid + off];
    __syncthreads();
  }
  const int add = lds[0];
  const int base = bid * 1024 + tid * 4;
  #pragma unroll
  for (int k = 0; k < 4; ++k) {
    int i = base + k;
    if (i < n) {
      int o = offsets[i] + add;
      offsets[i] = o;
      cursor[i] = o;
    }
  }
  if (bid == 0 && tid == 0) offsets[n] = n_edges;
}

// ================== scatter: 4 edges/thread via int4 =======================
__global__ __launch_bounds__(256) void scatter_kernel(
    const int* __restrict__ eidx, const int* __restrict__ etype,
    int* __restrict__ cursor, unsigned int* __restrict__ packed, int n_edges) {
  const int e0 = (blockIdx.x * 256 + threadIdx.x) * 4;
  if (e0 + 3 < n_edges) {
    const int4 s4 = *(const int4*)&eidx[e0];
    const int4 t4 = *(const int4*)&eidx[n_edges + e0];
    const int4 y4 = *(const int4*)&etype[e0];
    int pos;
    pos = atomicAdd(&cursor[t4.x], 1);
    packed[pos] = (unsigned int)s4.x | ((unsigned int)y4.x << 17);
    pos = atomicAdd(&cursor[t4.y], 1);
    packed[pos] = (unsigned int)s4.y | ((unsigned int)y4.y << 17);
    pos = atomicAdd(&cursor[t4.z], 1);
    packed[pos] = (unsigned int)s4.z | ((unsigned int)y4.z << 17);
    pos = atomicAdd(&cursor[t4.w], 1);
    packed[pos] = (unsigned int)s4.w | ((unsigned int)y4.w << 17);
  } else {
    for (int e = e0; e < n_edges; ++e) {
      const int pos = atomicAdd(&cursor[eidx[n_edges + e]], 1);
      packed[pos] = (unsigned int)eidx[e] | ((unsigned int)etype[e] << 17);
    }
  }
}

// ================ aggregate: 2 nodes per wave, 8-deep pipeline =============
// out[n] = relu(h[n] + sum_{edges->n} (h[src] + em[etype])); h,em bf16.
// Lane covers 4 dims via uint2 (8B); invalid edges -> zero rows (predicated).
__global__ __launch_bounds__(256) void aggregate_kernel(
    const int* __restrict__ offsets, const unsigned int* __restrict__ packed,
    const uint2* __restrict__ e4, const uint2* __restrict__ h4,
    float* __restrict__ out, int n_nodes, int n_edges, unsigned int zero_p) {
  const int gid = blockIdx.x * 256 + threadIdx.x;
  const int lane = threadIdx.x & 63;
  const int half = lane >> 5;
  const int sl = lane & 31;
  const int n = (gid >> 6) * 2 + half;
  if (n >= n_nodes) return;

  const uint2 sb = h4[(size_t)n * 32 + sl];  // self (4 bf16)
  float a0 = bflo(sb.x), a1 = bfhi(sb.x), a2 = bflo(sb.y), a3 = bfhi(sb.y);
  float c0 = 0.f, c1 = 0.f, c2 = 0.f, c3 = 0.f;

  int j = offsets[n];
  const int end = offsets[n + 1];
  int trips = (end - j + 7) >> 3;
  int to = __shfl_xor(trips, 32);
  const int T = trips > to ? trips : to;
  const int emax = n_edges - 1;

  for (int t = 0; t < T; ++t, j += 8) {
    unsigned int p[8];
    #pragma unroll
    for (int u = 0; u < 8; ++u) {
      const int ju = j + u;
      const unsigned int pu = packed[ju <= emax ? ju : emax];
      p[u] = (ju < end) ? pu : zero_p;
    }
    uint2 g[8], ev[8];
    #pragma unroll
    for (int u = 0; u < 8; ++u)
      g[u] = h4[(size_t)(p[u] & 0x1FFFFu) * 32 + sl];
    #pragma unroll
    for (int u = 0; u < 8; ++u)
      ev[u] = e4[(p[u] >> 17) * 32 + sl];
    #pragma unroll
    for (int u = 0; u < 8; u += 2) {
      a0 += bflo(g[u].x) + bflo(ev[u].x);
      a1 += bfhi(g[u].x) + bfhi(ev[u].x);
      a2 += bflo(g[u].y) + bflo(ev[u].y);
      a3 += bfhi(g[u].y) + bfhi(ev[u].y);
      c0 += bflo(g[u + 1].x) + bflo(ev[u + 1].x);
      c1 += bfhi(g[u + 1].x) + bfhi(ev[u + 1].x);
      c2 += bflo(g[u + 1].y) + bflo(ev[u + 1].y);
      c3 += bfhi(g[u + 1].y) + bfhi(ev[u + 1].y);
    }
  }

  float4 r;
  r.x = fmaxf(a0 + c0, 0.f);
  r.y = fmaxf(a1 + c1, 0.f);
  r.z = fmaxf(a2 + c2, 0.f);
  r.w = fmaxf(a3 + c3, 0.f);
  ((float4*)out)[(size_t)n * 32 + sl] = r;
}

// ===========================================================================
extern "C" void kernel_launch(void* const* d_in, const int* in_sizes, int n_in,
                              void* d_out, int out_size, void* d_ws,
                              size_t ws_size, hipStream_t stream) {
  const float* nf   = (const float*)d_in[0];  // (N, 128) f32
  const int*   eidx = (const int*)d_in[1];    // (2, E) int
  const int*   etyp = (const int*)d_in[2];    // (E,) int
  const float* eemb = (const float*)d_in[3];  // (64, 128) f32
  const float* W    = (const float*)d_in[4];  // (128, 128) f32
  const float* b    = (const float*)d_in[5];  // (128,) f32

  const int n_nodes = in_sizes[0] / D;  // 100000
  const int n_edges = in_sizes[2];      // 625000

  float* out = (float*)d_out;

  // workspace layout (~29.5 MB); 16B alignment maintained
  char* base = (char*)d_ws;
  unsigned short* Wt = (unsigned short*)base;                  // 32 KB
  unsigned short* em_bf = (unsigned short*)(base + 32768);     // 65 rows
  unsigned short* h_bf = (unsigned short*)(base + 65536);      // (N+1)*128 bf16
  char* tail = base + 65536 + (size_t)(n_nodes + 1) * D * 2;
  int* counts = (int*)tail;
  int* offsets = counts + n_nodes;
  int* cursor = offsets + (n_nodes + 1);
  int* blockSums = cursor + n_nodes;
  unsigned int* packed = (unsigned int*)(blockSums + 1024);    // E uints

  const int nb = (n_nodes + 1023) / 1024;        // 98 scan blocks (<=256)
  const int gemmBlocks = (n_nodes + 63) / 64;    // 1563
  const int epb = (n_edges + gemmBlocks - 1) / gemmBlocks;  // 400

  // 1) prep: Wt transpose+cast, em cast, zero counts + sentinel rows
  prep_kernel<<<(n_nodes + 255) / 256, 256, 0, stream>>>(W, eemb, Wt, em_bf,
                                                         h_bf, counts, n_nodes);

  // 2) GEMM h_bf = bf16(nf @ W + b) + fused histogram
  gemm_h_kernel<<<gemmBlocks, 256, 0, stream>>>(
      nf, Wt, b, h_bf, eidx + n_edges, counts, n_nodes, n_edges, epb);

  // 3) scan (2 kernels)
  scan1_kernel<<<nb, 256, 0, stream>>>(counts, offsets, blockSums, n_nodes);
  scan23_kernel<<<nb, 256, 0, stream>>>(offsets, cursor, blockSums, nb,
                                        n_nodes, n_edges);

  // 4) scatter packed (src|etype) by target
  scatter_kernel<<<(n_edges + 1023) / 1024, 256, 0, stream>>>(
      eidx, etyp, cursor, packed, n_edges);

  // 5) aggregate + self + ReLU (2 nodes/wave, 8-deep)
  const unsigned int zero_p = (unsigned int)n_nodes | (64u << 17);
  const int aggBlocks = (n_nodes + 7) / 8;  // 8 nodes per 256-thread block
  aggregate_kernel<<<aggBlocks, 256, 0, stream>>>(
      offsets, packed, (const uint2*)em_bf, (const uint2*)h_bf, out, n_nodes,
      n_edges, zero_p);
}

// Round 8
// 131.043 us; speedup vs baseline: 4.5034x; 1.0935x over previous
//
#include <hip/hip_runtime.h>
#include <hip/hip_bf16.h>

#define D 128  // D_IN == D_OUT == 128

typedef __attribute__((ext_vector_type(8))) short short8v;   // 8 bf16 (4 VGPR)
typedef __attribute__((ext_vector_type(4))) float float4v;   // MFMA acc

__device__ __forceinline__ unsigned short f2bf(float f) {
  union { float f; unsigned int u; } v; v.f = f;
  unsigned int r = v.u + 0x7fffu + ((v.u >> 16) & 1u);  // RNE
  return (unsigned short)(r >> 16);
}
// packed pair conversion -> v_cvt_pk_bf16_f32 (RNE)
__device__ __forceinline__ unsigned int pkbf(float lo, float hi) {
  float2 f; f.x = lo; f.y = hi;
  __hip_bfloat162 v = __float22bfloat162_rn(f);
  union { __hip_bfloat162 b; unsigned int u; } c; c.b = v;
  return c.u;
}
__device__ __forceinline__ float bflo(unsigned int u) {
  union { unsigned int v; float f; } c; c.v = u << 16; return c.f;
}
__device__ __forceinline__ float bfhi(unsigned int u) {
  union { unsigned int v; float f; } c; c.v = u & 0xffff0000u; return c.f;
}

// == prep: Wt[n][k]=bf16(W[k][n]); em_bf=bf16(eemb); zero counts+sentinels ==
__global__ __launch_bounds__(256) void prep_kernel(
    const float* __restrict__ W, const float* __restrict__ eemb,
    unsigned short* __restrict__ Wt, unsigned short* __restrict__ em_bf,
    unsigned short* __restrict__ h_bf, int* __restrict__ counts,
    int n_nodes) {
  int i = blockIdx.x * 256 + threadIdx.x;
  if (i < D * D) Wt[i] = f2bf(W[(i & 127) * D + (i >> 7)]);      // transpose
  if (i < 64 * D) em_bf[i] = f2bf(eemb[i]);
  if (i < 64) ((unsigned int*)(h_bf + (size_t)n_nodes * D))[i] = 0u;
  if (i >= 64 && i < 128) ((unsigned int*)(em_bf + 64 * D))[i - 64] = 0u;
  if (i < n_nodes) counts[i] = 0;  // replaces hipMemsetAsync
}

// ======== GEMM (swapped MFMA), global_load_lds staging + fused hist ========
// Block 256 = 4 waves; tile = 64 nodes x 128 cols; X staged as f32 (32 KB)
// via global_load_lds with source-side XOR swizzle:
//   LDS[o] = global[swz(o)], swz(o) = o ^ (((o>>9)&7)<<4)   (bijective)
// Fragment reads apply the same swizzle -> 2-way banks (free).
__global__ __launch_bounds__(256) void gemm_h_kernel(
    const float* __restrict__ nf, const unsigned short* __restrict__ Wt,
    const float* __restrict__ b, unsigned short* __restrict__ h_bf,
    const int* __restrict__ eidx_tgt, int* __restrict__ counts,
    int n_nodes, int n_edges, int epb) {
  __shared__ float Xs[64 * D];  // 32 KB f32, swizzled residency
  const int tid = threadIdx.x;
  const int wv = tid >> 6;
  const int ln = tid & 63;
  const int nodeBase = blockIdx.x * 64;

  const char* nf_tile = (const char*)(nf + (size_t)nodeBase * D);
  char* xs_b = (char*)Xs;

  // ---- stage X tile: fire-and-forget DMA (fast path), guarded tail ----
  if (nodeBase + 64 <= n_nodes) {
    #pragma unroll
    for (int it = 0; it < 8; ++it) {
      const int doff = wv * 8192 + it * 1024;        // wave-uniform LDS base
      const int off = doff + ln * 16;                // this lane's 16B chunk
      const int src = off ^ (((off >> 9) & 7) << 4);
      __builtin_amdgcn_global_load_lds(
          (const __attribute__((address_space(1))) unsigned int*)(nf_tile + src),
          (__attribute__((address_space(3))) unsigned int*)(xs_b + doff),
          16, 0, 0);
    }
  } else {
    #pragma unroll
    for (int it = 0; it < 8; ++it) {
      const int off = (it * 256 + tid) * 16;
      const int src = off ^ (((off >> 9) & 7) << 4);
      const int row = src >> 9;
      float4 v = {0.f, 0.f, 0.f, 0.f};
      if (nodeBase + row < n_nodes) v = *(const float4*)(nf_tile + src);
      *(float4*)(xs_b + off) = v;
    }
  }

  // ---- fused histogram: issue now, retire under MFMA ----
  {
    const int ebase = blockIdx.x * epb;
    int eend = ebase + epb;
    if (eend > n_edges) eend = n_edges;
    for (int e = ebase + tid; e < eend; e += 256)
      atomicAdd(&counts[eidx_tgt[e]], 1);
  }

  const int m = ln & 15;
  const int q = ln >> 4;
  const int n0 = (wv & 1) * 64;        // h-col half for this wave
  const int nodeHalf = (wv >> 1) * 32; // node half for this wave

  // ---- A fragments (Wt rows = h cols) from L2-hot global ----
  short8v afrag[4][4];  // [n-tile][k-chunk]
  #pragma unroll
  for (int nt = 0; nt < 4; ++nt) {
    const int n = n0 + nt * 16 + m;
    #pragma unroll
    for (int kc = 0; kc < 4; ++kc)
      afrag[nt][kc] = *(const short8v*)&Wt[n * D + kc * 32 + q * 8];
  }

  float4v acc[4][2] = {};
  __syncthreads();  // drains vmcnt (staging + atomics)

  #pragma unroll
  for (int kc = 0; kc < 4; ++kc) {
    #pragma unroll
    for (int t = 0; t < 2; ++t) {
      const int node = nodeHalf + t * 16 + m;
      const int ba = node * 512 + kc * 128 + q * 32;
      const int sw = (node & 7) << 4;
      const float4 x0 = *(const float4*)(xs_b + (ba ^ sw));
      const float4 x1 = *(const float4*)(xs_b + ((ba + 16) ^ sw));
      union { unsigned int u[4]; short8v s; } cv;
      cv.u[0] = pkbf(x0.x, x0.y);
      cv.u[1] = pkbf(x0.z, x0.w);
      cv.u[2] = pkbf(x1.x, x1.y);
      cv.u[3] = pkbf(x1.z, x1.w);
      const short8v bv = cv.s;
      #pragma unroll
      for (int nt = 0; nt < 4; ++nt)
        acc[nt][t] = __builtin_amdgcn_mfma_f32_16x16x32_bf16(
            afrag[nt][kc], bv, acc[nt][t], 0, 0, 0);
    }
  }

  // ---- epilogue: +bias, cvt_pk, 8B stores ----
  #pragma unroll
  for (int nt = 0; nt < 4; ++nt) {
    const int colBase = n0 + nt * 16 + q * 4;
    const float4 bv = *(const float4*)&b[colBase];
    #pragma unroll
    for (int t = 0; t < 2; ++t) {
      const int node = nodeBase + nodeHalf + t * 16 + m;
      if (node < n_nodes) {
        uint2 val;
        val.x = pkbf(acc[nt][t][0] + bv.x, acc[nt][t][1] + bv.y);
        val.y = pkbf(acc[nt][t][2] + bv.z, acc[nt][t][3] + bv.w);
        *(uint2*)&h_bf[(size_t)node * D + colBase] = val;
      }
    }
  }
}

// ============================ scan =========================================
// pass 1: per-block (1024 elems) local exclusive scan; blockSums[b] = total
__global__ __launch_bounds__(256) void scan1_kernel(
    const int* __restrict__ counts, int* __restrict__ offsets,
    int* __restrict__ blockSums, int n) {
  __shared__ int lds[256];
  const int tid = threadIdx.x;
  const int base = blockIdx.x * 1024 + tid * 4;
  int v[4];
  #pragma unroll
  for (int k = 0; k < 4; ++k) v[k] = (base + k < n) ? counts[base + k] : 0;
  int s = v[0] + v[1] + v[2] + v[3];
  lds[tid] = s;
  for (int off = 1; off < 256; off <<= 1) {
    __syncthreads();
    int t = (tid >= off) ? lds[tid - off] : 0;
    __syncthreads();
    lds[tid] += t;
  }
  __syncthreads();
  int run = lds[tid] - s;
  #pragma unroll
  for (int k = 0; k < 4; ++k) {
    if (base + k < n) offsets[base + k] = run;
    run += v[k];
  }
  if (tid == 255) blockSums[blockIdx.x] = lds[255];
}

// pass 2 (fused scan2+scan3): each block reduces blockSums[0..bid-1] in LDS,
// adds to its 1024 offsets, copies to cursor. Requires nb <= 256.
__global__ __launch_bounds__(256) void scan23_kernel(
    int* __restrict__ offsets, int* __restrict__ cursor,
    const int* __restrict__ blockSums, int nb, int n, int n_edges) {
  __shared__ int lds[256];
  const int tid = threadIdx.x;
  const int bid = blockIdx.x;
  lds[tid] = (tid < bid && tid < nb) ? blockSums[tid] : 0;
  __syncthreads();
  #pragma unroll
  for (int off = 128; off > 0; off >>= 1) {
    if (tid < off) lds[tid] += lds[tid + off];
    __syncthreads();
  }
  const int add = lds[0];
  const int base = bid * 1024 + tid * 4;
  #pragma unroll
  for (int k = 0; k < 4; ++k) {
    int i = base + k;
    if (i < n) {
      int o = offsets[i] + add;
      offsets[i] = o;
      cursor[i] = o;
    }
  }
  if (bid == 0 && tid == 0) offsets[n] = n_edges;
}

// ================== scatter: 4 edges/thread via int4 =======================
__global__ __launch_bounds__(256) void scatter_kernel(
    const int* __restrict__ eidx, const int* __restrict__ etype,
    int* __restrict__ cursor, unsigned int* __restrict__ packed, int n_edges) {
  const int e0 = (blockIdx.x * 256 + threadIdx.x) * 4;
  if (e0 + 3 < n_edges) {
    const int4 s4 = *(const int4*)&eidx[e0];
    const int4 t4 = *(const int4*)&eidx[n_edges + e0];
    const int4 y4 = *(const int4*)&etype[e0];
    int pos;
    pos = atomicAdd(&cursor[t4.x], 1);
    packed[pos] = (unsigned int)s4.x | ((unsigned int)y4.x << 17);
    pos = atomicAdd(&cursor[t4.y], 1);
    packed[pos] = (unsigned int)s4.y | ((unsigned int)y4.y << 17);
    pos = atomicAdd(&cursor[t4.z], 1);
    packed[pos] = (unsigned int)s4.z | ((unsigned int)y4.z << 17);
    pos = atomicAdd(&cursor[t4.w], 1);
    packed[pos] = (unsigned int)s4.w | ((unsigned int)y4.w << 17);
  } else {
    for (int e = e0; e < n_edges; ++e) {
      const int pos = atomicAdd(&cursor[eidx[n_edges + e]], 1);
      packed[pos] = (unsigned int)eidx[e] | ((unsigned int)etype[e] << 17);
    }
  }
}

// ================ aggregate: 2 nodes per wave, 8-deep pipeline =============
// out[n] = relu(h[n] + sum_{edges->n} (h[src] + em[etype])); h,em bf16.
// Lane covers 4 dims via uint2 (8B); invalid edges -> zero rows (predicated).
__global__ __launch_bounds__(256) void aggregate_kernel(
    const int* __restrict__ offsets, const unsigned int* __restrict__ packed,
    const uint2* __restrict__ e4, const uint2* __restrict__ h4,
    float* __restrict__ out, int n_nodes, int n_edges, unsigned int zero_p) {
  const int gid = blockIdx.x * 256 + threadIdx.x;
  const int lane = threadIdx.x & 63;
  const int half = lane >> 5;
  const int sl = lane & 31;
  const int n = (gid >> 6) * 2 + half;
  if (n >= n_nodes) return;

  const uint2 sb = h4[(size_t)n * 32 + sl];  // self (4 bf16)
  float a0 = bflo(sb.x), a1 = bfhi(sb.x), a2 = bflo(sb.y), a3 = bfhi(sb.y);
  float c0 = 0.f, c1 = 0.f, c2 = 0.f, c3 = 0.f;

  int j = offsets[n];
  const int end = offsets[n + 1];
  int trips = (end - j + 7) >> 3;
  int to = __shfl_xor(trips, 32);
  const int T = trips > to ? trips : to;
  const int emax = n_edges - 1;

  for (int t = 0; t < T; ++t, j += 8) {
    unsigned int p[8];
    #pragma unroll
    for (int u = 0; u < 8; ++u) {
      const int ju = j + u;
      const unsigned int pu = packed[ju <= emax ? ju : emax];
      p[u] = (ju < end) ? pu : zero_p;
    }
    uint2 g[8], ev[8];
    #pragma unroll
    for (int u = 0; u < 8; ++u)
      g[u] = h4[(size_t)(p[u] & 0x1FFFFu) * 32 + sl];
    #pragma unroll
    for (int u = 0; u < 8; ++u)
      ev[u] = e4[(p[u] >> 17) * 32 + sl];
    #pragma unroll
    for (int u = 0; u < 8; u += 2) {
      a0 += bflo(g[u].x) + bflo(ev[u].x);
      a1 += bfhi(g[u].x) + bfhi(ev[u].x);
      a2 += bflo(g[u].y) + bflo(ev[u].y);
      a3 += bfhi(g[u].y) + bfhi(ev[u].y);
      c0 += bflo(g[u + 1].x) + bflo(ev[u + 1].x);
      c1 += bfhi(g[u + 1].x) + bfhi(ev[u + 1].x);
      c2 += bflo(g[u + 1].y) + bflo(ev[u + 1].y);
      c3 += bfhi(g[u + 1].y) + bfhi(ev[u + 1].y);
    }
  }

  float4 r;
  r.x = fmaxf(a0 + c0, 0.f);
  r.y = fmaxf(a1 + c1, 0.f);
  r.z = fmaxf(a2 + c2, 0.f);
  r.w = fmaxf(a3 + c3, 0.f);
  ((float4*)out)[(size_t)n * 32 + sl] = r;
}

// ===========================================================================
extern "C" void kernel_launch(void* const* d_in, const int* in_sizes, int n_in,
                              void* d_out, int out_size, void* d_ws,
                              size_t ws_size, hipStream_t stream) {
  const float* nf   = (const float*)d_in[0];  // (N, 128) f32
  const int*   eidx = (const int*)d_in[1];    // (2, E) int
  const int*   etyp = (const int*)d_in[2];    // (E,) int
  const float* eemb = (const float*)d_in[3];  // (64, 128) f32
  const float* W    = (const float*)d_in[4];  // (128, 128) f32
  const float* b    = (const float*)d_in[5];  // (128,) f32

  const int n_nodes = in_sizes[0] / D;  // 100000
  const int n_edges = in_sizes[2];      // 625000

  float* out = (float*)d_out;

  // workspace layout (~29.5 MB); 16B alignment maintained
  char* base = (char*)d_ws;
  unsigned short* Wt = (unsigned short*)base;                  // 32 KB
  unsigned short* em_bf = (unsigned short*)(base + 32768);     // 65 rows
  unsigned short* h_bf = (unsigned short*)(base + 65536);      // (N+1)*128 bf16
  char* tail = base + 65536 + (size_t)(n_nodes + 1) * D * 2;
  int* counts = (int*)tail;
  int* offsets = counts + n_nodes;
  int* cursor = offsets + (n_nodes + 1);
  int* blockSums = cursor + n_nodes;
  unsigned int* packed = (unsigned int*)(blockSums + 1024);    // E uints

  const int nb = (n_nodes + 1023) / 1024;        // 98 scan blocks (<=256)
  const int gemmBlocks = (n_nodes + 63) / 64;    // 1563
  const int epb = (n_edges + gemmBlocks - 1) / gemmBlocks;  // 400

  // 1) prep: Wt transpose+cast, em cast, zero counts + sentinel rows
  prep_kernel<<<(n_nodes + 255) / 256, 256, 0, stream>>>(W, eemb, Wt, em_bf,
                                                         h_bf, counts, n_nodes);

  // 2) GEMM h_bf = bf16(nf @ W + b) + fused histogram
  gemm_h_kernel<<<gemmBlocks, 256, 0, stream>>>(
      nf, Wt, b, h_bf, eidx + n_edges, counts, n_nodes, n_edges, epb);

  // 3) scan (2 kernels)
  scan1_kernel<<<nb, 256, 0, stream>>>(counts, offsets, blockSums, n_nodes);
  scan23_kernel<<<nb, 256, 0, stream>>>(offsets, cursor, blockSums, nb,
                                        n_nodes, n_edges);

  // 4) scatter packed (src|etype) by target
  scatter_kernel<<<(n_edges + 1023) / 1024, 256, 0, stream>>>(
      eidx, etyp, cursor, packed, n_edges);

  // 5) aggregate + self + ReLU (2 nodes/wave, 8-deep)
  const unsigned int zero_p = (unsigned int)n_nodes | (64u << 17);
  const int aggBlocks = (n_nodes + 7) / 8;  // 8 nodes per 256-thread block
  aggregate_kernel<<<aggBlocks, 256, 0, stream>>>(
      offsets, packed, (const uint2*)em_bf, (const uint2*)h_bf, out, n_nodes,
      n_edges, zero_p);
}